// Round 4
// baseline (415.546 us; speedup 1.0000x reference)
//
#include <hip/hip_runtime.h>
#include <hip/hip_bf16.h>
#include <math.h>

#define RR 1024
#define BB 16
#define DD 1024
#define K_ACTIVE 20
#define NBLK 1024   // 4 blocks/CU x 256 CUs: all co-resident (required for grid_sync)

typedef float vfloat4 __attribute__((ext_vector_type(4)));

// Device-scope grid barrier. Safe because all NBLK blocks are co-resident
// (launch_bounds(256,4) caps VGPR at 128 -> 4 blocks/CU; LDS 5.1KB -> 31/CU).
// __threadfence() before arrive = release (L2 writeback on CDNA4);
// __threadfence() after spin = acquire (L1/L2 invalidate) so cross-XCD
// producer data (adj, hard) is visible.
__device__ __forceinline__ void grid_sync(int* cnt) {
    __syncthreads();
    if (threadIdx.x == 0) {
        __threadfence();
        atomicAdd(cnt, 1);
        while (__hip_atomic_load(cnt, __ATOMIC_RELAXED, __HIP_MEMORY_SCOPE_AGENT) < NBLK)
            __builtin_amdgcn_s_sleep(1);
        __threadfence();
    }
    __syncthreads();
}

__global__ __launch_bounds__(256, 4) void fused_kernel(
    const float* __restrict__ H, const float* __restrict__ msg,
    const float* __restrict__ w, const float* __restrict__ theta,
    const float* __restrict__ refr, const float* __restrict__ fb,
    const int* __restrict__ nbrs,
    float* __restrict__ Hs, float* __restrict__ hard, float* __restrict__ adj,
    int* __restrict__ cnt)
{
    __shared__ float val[RR];
    __shared__ unsigned char sel[RR];

    const int lane = threadIdx.x & 63;
    const int wgid = (blockIdx.x << 2) + (threadIdx.x >> 6);   // 0..4095

    // ---------------- Phase 1: adj[b,r] = H.w - theta - refr - 0.5*fb_new ----
    // w fragment loaded once per wave, reused for 4 pairs.
    const vfloat4* __restrict__ W4 = (const vfloat4*)w;
    const vfloat4 w0 = W4[lane],       w1 = W4[lane + 64];
    const vfloat4 w2 = W4[lane + 128], w3 = W4[lane + 192];

#pragma unroll
    for (int p = 0; p < 4; ++p) {
        const int pair = wgid + 4096 * p;      // pair = r*BB + b
        const int r = pair >> 4;
        const int b = pair & 15;
        const vfloat4* __restrict__ H4 = (const vfloat4*)(H + (size_t)pair * DD);
        const vfloat4* __restrict__ M4 = (const vfloat4*)(msg + (size_t)pair * DD);

        const vfloat4 h0 = H4[lane],       h1 = H4[lane + 64];
        const vfloat4 h2 = H4[lane + 128], h3 = H4[lane + 192];
        const vfloat4 m0 = M4[lane],       m1 = M4[lane + 64];
        const vfloat4 m2 = M4[lane + 128], m3 = M4[lane + 192];

        float dot = h0.x * w0.x + h0.y * w0.y + h0.z * w0.z + h0.w * w0.w;
        dot += h1.x * w1.x + h1.y * w1.y + h1.z * w1.z + h1.w * w1.w;
        dot += h2.x * w2.x + h2.y * w2.y + h2.z * w2.z + h2.w * w2.w;
        dot += h3.x * w3.x + h3.y * w3.y + h3.z * w3.z + h3.w * w3.w;

        float ss = m0.x * m0.x + m0.y * m0.y + m0.z * m0.z + m0.w * m0.w;
        ss += m1.x * m1.x + m1.y * m1.y + m1.z * m1.z + m1.w * m1.w;
        ss += m2.x * m2.x + m2.y * m2.y + m2.z * m2.z + m2.w * m2.w;
        ss += m3.x * m3.x + m3.y * m3.y + m3.z * m3.z + m3.w * m3.w;

#pragma unroll
        for (int off = 32; off > 0; off >>= 1) {
            dot += __shfl_down(dot, off);
            ss  += __shfl_down(ss, off);
        }
        if (lane == 0) {
            const float fb_mag = sqrtf(ss);
            const float fb_new = 0.9f * fb[b * RR + r] + 0.1f * fb_mag;
            adj[b * RR + r] = dot - theta[r] - refr[b * RR + r] - 0.5f * fb_new;
        }
    }

    grid_sync(&cnt[0]);

    // ---------------- Phase 2: greedy hex NMS, wave 0 of blocks 0..15 --------
    // Single-wave: no __syncthreads needed; LDS ordering is intra-wave.
    // Equivalent to the reference scan over argsort(-adj): iterated argmax
    // over non-suppressed entries, tie -> lowest index (stable sort order).
    if (blockIdx.x < BB && threadIdx.x < 64) {
        const int b = blockIdx.x;
#pragma unroll
        for (int j = 0; j < 16; ++j) {
            const int i = lane + 64 * j;
            val[i] = adj[b * RR + i];
            sel[i] = 0;
        }
        for (int it = 0; it < K_ACTIVE; ++it) {
            float m = -INFINITY;
            int mi = RR;
#pragma unroll
            for (int j = 0; j < 16; ++j) {
                const int i = lane + 64 * j;
                const float v = val[i];
                if (v > m || (v == m && i < mi)) { m = v; mi = i; }
            }
#pragma unroll
            for (int off = 32; off > 0; off >>= 1) {
                const float ov = __shfl_down(m, off);
                const int   oi = __shfl_down(mi, off);
                if (ov > m || (ov == m && oi < mi)) { m = ov; mi = oi; }
            }
            const int   bi = __shfl(mi, 0);
            const float bm = __shfl(m, 0);
            if (bm > -INFINITY) {
                if (lane == 0) { sel[bi] = 1; val[bi] = -INFINITY; }
                if (lane < 6)  { val[nbrs[bi * 6 + lane]] = -INFINITY; }
            }
        }
#pragma unroll
        for (int j = 0; j < 16; ++j) {
            const int i = lane + 64 * j;
            hard[b * RR + i] = sel[i] ? 1.0f : 0.0f;
        }
    }

    grid_sync(&cnt[1]);

    // ---------------- Phase 3: Hs = H * hard (0/1 gate) ----------------------
    // Gated-off rows (~98%) write zeros without reading H; nontemporal stores
    // (write-once output, never re-read).
#pragma unroll
    for (int p = 0; p < 4; ++p) {
        const int pair = wgid + 4096 * p;
        const int r = pair >> 4;
        const int b = pair & 15;
        const float g = hard[b * RR + r];
        vfloat4* out4 = (vfloat4*)(Hs + (size_t)pair * DD);
        if (g != 0.0f) {
            const vfloat4* H4 = (const vfloat4*)(H + (size_t)pair * DD);
            const vfloat4 v0 = H4[lane],       v1 = H4[lane + 64];
            const vfloat4 v2 = H4[lane + 128], v3 = H4[lane + 192];
            __builtin_nontemporal_store(v0, &out4[lane]);
            __builtin_nontemporal_store(v1, &out4[lane + 64]);
            __builtin_nontemporal_store(v2, &out4[lane + 128]);
            __builtin_nontemporal_store(v3, &out4[lane + 192]);
        } else {
            const vfloat4 z = {0.f, 0.f, 0.f, 0.f};
            __builtin_nontemporal_store(z, &out4[lane]);
            __builtin_nontemporal_store(z, &out4[lane + 64]);
            __builtin_nontemporal_store(z, &out4[lane + 128]);
            __builtin_nontemporal_store(z, &out4[lane + 192]);
        }
    }
}

extern "C" void kernel_launch(void* const* d_in, const int* in_sizes, int n_in,
                              void* d_out, int out_size, void* d_ws, size_t ws_size,
                              hipStream_t stream) {
    const float* H     = (const float*)d_in[0];   // [R,B,D]
    const float* msg   = (const float*)d_in[1];   // [R,B,D]
    const float* w     = (const float*)d_in[2];   // [D]
    const float* theta = (const float*)d_in[3];   // [R]
    const float* refr  = (const float*)d_in[4];   // [B,R]
    const float* fb    = (const float*)d_in[5];   // [B,R]
    const int*   nbrs  = (const int*)d_in[6];     // [R,6]

    float* out  = (float*)d_out;
    float* Hs   = out;                                   // [R,B,D]
    float* hard = out + (size_t)RR * BB * DD;            // [B,R]
    float* adj  = hard + (size_t)BB * RR;                // [B,R]

    // zero the two grid-barrier counters (d_ws is re-poisoned to 0xAA before
    // every timed launch; this memset is captured in the graph and replays).
    hipMemsetAsync(d_ws, 0, 16, stream);
    fused_kernel<<<NBLK, 256, 0, stream>>>(H, msg, w, theta, refr, fb, nbrs,
                                           Hs, hard, adj, (int*)d_ws);
}

// Round 5
// 212.451 us; speedup vs baseline: 1.9560x; 1.9560x over previous
//
#include <hip/hip_runtime.h>
#include <hip/hip_bf16.h>
#include <math.h>

#define RR 1024
#define BB 16
#define DD 1024
#define K_ACTIVE 20

typedef float vfloat4 __attribute__((ext_vector_type(4)));

// ---------------------------------------------------------------------------
// Kernel 1: adj[b,r] = dot(H[r,b,:],w) - theta[r] - refr[b,r]
//                      - 0.5*(0.9*fb[b,r] + 0.1*||msg[r,b,:]||)
// Persistent form: 1024 blocks x 4 waves; each wave processes 4 pairs with
// double-buffered loads — while reducing pair p, pair p+1's 8 dwordx4 loads
// are in flight (s_waitcnt vmcnt(8) instead of a full drain per pair).
// w is loaded once per wave and reused for all 4 pairs.
// ---------------------------------------------------------------------------
__global__ __launch_bounds__(256, 4) void score_kernel(
    const float* __restrict__ H, const float* __restrict__ msg,
    const float* __restrict__ w, const float* __restrict__ theta,
    const float* __restrict__ refr, const float* __restrict__ fb,
    float* __restrict__ adj_out)
{
    const int wave = threadIdx.x >> 6;
    const int lane = threadIdx.x & 63;
    const int wid  = blockIdx.x * 4 + wave;   // 0..4095

    const vfloat4* __restrict__ W4 = (const vfloat4*)w;
    const vfloat4 w0 = W4[lane],       w1 = W4[lane + 64];
    const vfloat4 w2 = W4[lane + 128], w3 = W4[lane + 192];

    int pair = wid;                            // pair = r*BB + b
    const vfloat4* __restrict__ H4 = (const vfloat4*)(H + (size_t)pair * DD);
    const vfloat4* __restrict__ M4 = (const vfloat4*)(msg + (size_t)pair * DD);
    vfloat4 ha0 = H4[lane], ha1 = H4[lane + 64], ha2 = H4[lane + 128], ha3 = H4[lane + 192];
    vfloat4 ma0 = M4[lane], ma1 = M4[lane + 64], ma2 = M4[lane + 128], ma3 = M4[lane + 192];

#pragma unroll
    for (int p = 0; p < 4; ++p) {
        // issue next pair's loads BEFORE consuming current registers
        vfloat4 hb0 = {0,0,0,0}, hb1 = {0,0,0,0}, hb2 = {0,0,0,0}, hb3 = {0,0,0,0};
        vfloat4 mb0 = {0,0,0,0}, mb1 = {0,0,0,0}, mb2 = {0,0,0,0}, mb3 = {0,0,0,0};
        if (p < 3) {
            const int npair = pair + 4096;
            const vfloat4* __restrict__ Hn = (const vfloat4*)(H + (size_t)npair * DD);
            const vfloat4* __restrict__ Mn = (const vfloat4*)(msg + (size_t)npair * DD);
            hb0 = Hn[lane]; hb1 = Hn[lane + 64]; hb2 = Hn[lane + 128]; hb3 = Hn[lane + 192];
            mb0 = Mn[lane]; mb1 = Mn[lane + 64]; mb2 = Mn[lane + 128]; mb3 = Mn[lane + 192];
        }

        float dot = ha0.x * w0.x + ha0.y * w0.y + ha0.z * w0.z + ha0.w * w0.w;
        dot += ha1.x * w1.x + ha1.y * w1.y + ha1.z * w1.z + ha1.w * w1.w;
        dot += ha2.x * w2.x + ha2.y * w2.y + ha2.z * w2.z + ha2.w * w2.w;
        dot += ha3.x * w3.x + ha3.y * w3.y + ha3.z * w3.z + ha3.w * w3.w;

        float ss = ma0.x * ma0.x + ma0.y * ma0.y + ma0.z * ma0.z + ma0.w * ma0.w;
        ss += ma1.x * ma1.x + ma1.y * ma1.y + ma1.z * ma1.z + ma1.w * ma1.w;
        ss += ma2.x * ma2.x + ma2.y * ma2.y + ma2.z * ma2.z + ma2.w * ma2.w;
        ss += ma3.x * ma3.x + ma3.y * ma3.y + ma3.z * ma3.z + ma3.w * ma3.w;

#pragma unroll
        for (int off = 32; off > 0; off >>= 1) {
            dot += __shfl_down(dot, off);
            ss  += __shfl_down(ss, off);
        }
        if (lane == 0) {
            const int r = pair >> 4;
            const int b = pair & 15;
            const float fb_mag = sqrtf(ss);
            const float fb_new = 0.9f * fb[b * RR + r] + 0.1f * fb_mag;
            adj_out[b * RR + r] = dot - theta[r] - refr[b * RR + r] - 0.5f * fb_new;
        }

        // rotate buffers
        ha0 = hb0; ha1 = hb1; ha2 = hb2; ha3 = hb3;
        ma0 = mb0; ma1 = mb1; ma2 = mb2; ma3 = mb3;
        pair += 4096;
    }
}

// ---------------------------------------------------------------------------
// Kernel 2: greedy hex NMS — ONE WAVE per batch (16 blocks x 64 threads).
// Equivalent to the reference scan over argsort(-adj): iterated argmax over
// non-suppressed entries, tie -> lowest index (stable sort order).
// ---------------------------------------------------------------------------
__global__ __launch_bounds__(64) void nms_kernel(
    const float* __restrict__ adj, const int* __restrict__ nbrs,
    float* __restrict__ hard)
{
    __shared__ float val[RR];
    __shared__ int   nb[RR * 6];
    __shared__ unsigned char sel[RR];

    const int b = blockIdx.x;
    const int lane = threadIdx.x;   // 0..63

#pragma unroll
    for (int j = 0; j < 16; ++j) {
        const int i = lane + 64 * j;
        val[i] = adj[b * RR + i];
        sel[i] = 0;
    }
    const int4* nb4g = (const int4*)nbrs;
    int4* nb4s = (int4*)nb;
#pragma unroll
    for (int j = 0; j < 24; ++j)
        nb4s[lane + 64 * j] = nb4g[lane + 64 * j];
    __syncthreads();

    for (int it = 0; it < K_ACTIVE; ++it) {
        float m = -INFINITY;
        int mi = RR;
#pragma unroll
        for (int j = 0; j < 16; ++j) {
            const int i = lane + 64 * j;
            const float v = val[i];
            if (v > m || (v == m && i < mi)) { m = v; mi = i; }
        }
#pragma unroll
        for (int off = 32; off > 0; off >>= 1) {
            const float ov = __shfl_down(m, off);
            const int   oi = __shfl_down(mi, off);
            if (ov > m || (ov == m && oi < mi)) { m = ov; mi = oi; }
        }
        const int   bi = __shfl(mi, 0);
        const float bm = __shfl(m, 0);
        if (bm > -INFINITY) {
            if (lane == 0) { sel[bi] = 1; val[bi] = -INFINITY; }
            if (lane < 6)  { val[nb[bi * 6 + lane]] = -INFINITY; }
        }
        __syncthreads();
    }

#pragma unroll
    for (int j = 0; j < 16; ++j) {
        const int i = lane + 64 * j;
        hard[b * RR + i] = sel[i] ? 1.0f : 0.0f;
    }
}

// ---------------------------------------------------------------------------
// Kernel 3: Hs[r,b,:] = hard[b,r] ? H[r,b,:] : 0. Persistent: 1024 blocks x
// 4 waves, each wave handles 4 pairs; gates preloaded up front; plain stores.
// Gated-off rows (~98%) write zeros without reading H.
// ---------------------------------------------------------------------------
__global__ __launch_bounds__(256, 4) void gate_kernel(
    const float* __restrict__ H, const float* __restrict__ hard,
    float* __restrict__ Hs)
{
    const int wave = threadIdx.x >> 6;
    const int lane = threadIdx.x & 63;
    const int wid  = blockIdx.x * 4 + wave;   // 0..4095

    // preload the 4 gate values (independent scalar loads, all in flight)
    float g[4];
#pragma unroll
    for (int p = 0; p < 4; ++p) {
        const int pair = wid + 4096 * p;
        g[p] = hard[(pair & 15) * RR + (pair >> 4)];
    }

#pragma unroll
    for (int p = 0; p < 4; ++p) {
        const int pair = wid + 4096 * p;
        vfloat4* out4 = (vfloat4*)(Hs + (size_t)pair * DD);
        if (g[p] != 0.0f) {
            const vfloat4* __restrict__ H4 = (const vfloat4*)(H + (size_t)pair * DD);
            const vfloat4 v0 = H4[lane],       v1 = H4[lane + 64];
            const vfloat4 v2 = H4[lane + 128], v3 = H4[lane + 192];
            out4[lane]       = v0;
            out4[lane + 64]  = v1;
            out4[lane + 128] = v2;
            out4[lane + 192] = v3;
        } else {
            const vfloat4 z = {0.f, 0.f, 0.f, 0.f};
            out4[lane]       = z;
            out4[lane + 64]  = z;
            out4[lane + 128] = z;
            out4[lane + 192] = z;
        }
    }
}

extern "C" void kernel_launch(void* const* d_in, const int* in_sizes, int n_in,
                              void* d_out, int out_size, void* d_ws, size_t ws_size,
                              hipStream_t stream) {
    const float* H     = (const float*)d_in[0];   // [R,B,D]
    const float* msg   = (const float*)d_in[1];   // [R,B,D]
    const float* w     = (const float*)d_in[2];   // [D]
    const float* theta = (const float*)d_in[3];   // [R]
    const float* refr  = (const float*)d_in[4];   // [B,R]
    const float* fb    = (const float*)d_in[5];   // [B,R]
    const int*   nbrs  = (const int*)d_in[6];     // [R,6]

    float* out  = (float*)d_out;
    float* Hs   = out;                                   // [R,B,D]
    float* hard = out + (size_t)RR * BB * DD;            // [B,R]
    float* adj  = hard + (size_t)BB * RR;                // [B,R]

    score_kernel<<<1024, 256, 0, stream>>>(H, msg, w, theta, refr, fb, adj);
    nms_kernel<<<BB, 64, 0, stream>>>(adj, nbrs, hard);
    gate_kernel<<<1024, 256, 0, stream>>>(H, hard, Hs);
}